// Round 6
// baseline (125.662 us; speedup 1.0000x reference)
//
#include <hip/hip_runtime.h>
#include <stdint.h>

typedef __attribute__((ext_vector_type(8))) short short8;
typedef __attribute__((ext_vector_type(4))) short short4v;
typedef __attribute__((ext_vector_type(4))) float f32x4;

__device__ __forceinline__ short f2bf(float x) {
  union { float f; uint32_t u; } c; c.f = x;
  uint32_t r = (c.u + 0x7FFFu + ((c.u >> 16) & 1u)) >> 16;
  return (short)r;
}
__device__ __forceinline__ float b2f(short s) {
  union { uint32_t u; float f; } c; c.u = ((uint32_t)(uint16_t)s) << 16;
  return c.f;
}
__device__ __forceinline__ uint32_t pack2bf(float lo, float hi) {
  return ((uint32_t)(uint16_t)f2bf(hi) << 16) | (uint32_t)(uint16_t)f2bf(lo);
}

// ---------------- fp32 -> bf16 convert (vectorized) ----------------
__global__ __launch_bounds__(256) void cvt_kernel(const float* __restrict__ in,
                                                  short* __restrict__ out, int n4) {
  int i = blockIdx.x * 256 + threadIdx.x;
  const int stride = gridDim.x * 256;
  for (; i < n4; i += stride) {
    float4 v = reinterpret_cast<const float4*>(in)[i];
    short4v o;
    o.x = f2bf(v.x); o.y = f2bf(v.y); o.z = f2bf(v.z); o.w = f2bf(v.w);
    reinterpret_cast<short4v*>(out)[i] = o;
  }
}

// ------------- fp32 [K][N] -> bf16 [N][K] transpose-convert -------------
__global__ __launch_bounds__(256) void tcvt_kernel(const float* __restrict__ in,
                                                   short* __restrict__ out, int K, int N) {
  __shared__ __align__(16) short tile[32][33];
  const int nb = blockIdx.x * 32, kb = blockIdx.y * 32;
  const int tx = threadIdx.x & 31, ty = threadIdx.x >> 5; // 32 x 8
#pragma unroll
  for (int i = 0; i < 32; i += 8)
    tile[ty + i][tx] = f2bf(in[(size_t)(kb + ty + i) * N + nb + tx]);
  __syncthreads();
#pragma unroll
  for (int i = 0; i < 32; i += 8)
    out[(size_t)(nb + ty + i) * K + kb + tx] = tile[tx][ty + i];
}

// ------------- bf16 V-region transpose: qkv[b][kv][2048+c] -> vT[b][c][kv] -------------
__global__ __launch_bounds__(256) void vtrans_kernel(const short* __restrict__ qkvb,
                                                     short* __restrict__ vT) {
  __shared__ __align__(16) short tile[64][65];
  const int b = blockIdx.z;
  const int kv0 = blockIdx.x * 64, c0 = blockIdx.y * 64;
  const int tx = threadIdx.x & 15, ty = threadIdx.x >> 4; // 16 x 16
  const short* src = qkvb + (size_t)(b * 1024) * 3072 + 2048;
#pragma unroll
  for (int i = 0; i < 64; i += 16) {
    int r = ty + i;
#pragma unroll
    for (int j = 0; j < 4; ++j)
      tile[r][tx * 4 + j] = src[(size_t)(kv0 + r) * 3072 + c0 + tx * 4 + j];
  }
  __syncthreads();
  short* dst = vT + (size_t)b * 1024 * 1024;
#pragma unroll
  for (int i = 0; i < 64; i += 16) {
    int cc = ty + i;
#pragma unroll
    for (int j = 0; j < 4; ++j)
      dst[(size_t)(c0 + cc) * 1024 + kv0 + tx * 4 + j] = tile[tx * 4 + j][cc];
  }
}

// ------------- k-projection precompute: kproj[bh][t] = dot(K[b,t,h,0:3], dir_h) -------------
__global__ __launch_bounds__(256) void kproj_kernel(const short* __restrict__ qkvb,
                                                    const float* __restrict__ hdirs,
                                                    float* __restrict__ kproj) {
  const int i = blockIdx.x * 256 + threadIdx.x; // over 32*1024
  const int bh = i >> 10, tt = i & 1023;
  const int b = bh >> 3, h = bh & 7;
  const float d0 = hdirs[h * 3], d1 = hdirs[h * 3 + 1], d2 = hdirs[h * 3 + 2];
  const short* kr = qkvb + (size_t)(b * 1024 + tt) * 3072 + 1024 + h * 128;
  kproj[i] = b2f(kr[0]) * d0 + b2f(kr[1]) * d1 + b2f(kr[2]) * d2;
}

// ================= 256x256 BK=64 8-phase GEMM (T1+T2+T3/T4+T5) =================
// C[M][N] = A[M][K] * Bt[N][K]^T, 512 threads = 8 waves (wr 0..1 x wc 0..3).
// LDS 128KB: Al/Bl [2 bufs][256][64] bf16, st_16x32 swizzle (byte ^= bit9<<5)
// applied via inverse-swizzled GLOBAL source (linear glds dest) + XOR'd ds_read.
// Phases per K-tile: (mg0,ng0),(mg0,ng1),(mg1,ng0),(mg1,ng1); region-freed
// staging: ph1->A2(t+1), ph2->B2(t+1), ph3->A1(t+2), ph4->B1(t+2); vmcnt(4)
// once per K-tile (never 0 mid-loop).
__device__ __forceinline__ void stage_half256(const short* __restrict__ gsrc,
                                              int K, short* lds_half,
                                              int w, int lane) {
#pragma unroll
  for (int i = 0; i < 2; ++i) {
    const int chunk = w * 2 + i;                 // 16 x 1KB chunks per half
    const int rr = chunk * 8 + (lane >> 3);      // row within half (0..127)
    const int cc = ((lane & 7) * 8) ^ (((rr >> 2) & 1) << 4); // pre-swizzled col
    const short* ga = gsrc + (size_t)rr * K + cc;
    __builtin_amdgcn_global_load_lds((const __attribute__((address_space(1))) void*)ga,
                                     (__attribute__((address_space(3))) void*)(lds_half + chunk * 512),
                                     16, 0, 0);
  }
}

template <int OUT_BF16>
__global__ __launch_bounds__(512, 2) void gemm256_kernel(const short* __restrict__ A,
                                                         const short* __restrict__ Bt,
                                                         void* __restrict__ Cout,
                                                         int K, int ldc, int nbx) {
  __shared__ __align__(16) short Al[2][256 * 64];
  __shared__ __align__(16) short Bl[2][256 * 64];
  const int t = threadIdx.x;
  const int lane = t & 63, w = t >> 6;
  const int wr = w >> 2, wc = w & 3;
  const int g = lane >> 4, c16 = lane & 15;
  // XCD-aware bijective swizzle (grid % 8 == 0 guaranteed by launch)
  const int nwg = gridDim.x;
  const int swz = (blockIdx.x & 7) * (nwg >> 3) + (blockIdx.x >> 3);
  const int row0 = (swz / nbx) * 256, col0 = (swz % nbx) * 256;

  f32x4 acc[8][4];
#pragma unroll
  for (int m = 0; m < 8; ++m)
#pragma unroll
    for (int n = 0; n < 4; ++n) {
      f32x4 z = {0.0f, 0.0f, 0.0f, 0.0f};
      acc[m][n] = z;
    }

  const int NT = K >> 6;
#define STAGE_A(H, KT, BUF) stage_half256(A + (size_t)(row0 + (H)*128) * K + (KT)*64, K, &Al[BUF][(H)*8192], w, lane)
#define STAGE_B(H, KT, BUF) stage_half256(Bt + (size_t)(col0 + (H)*128) * K + (KT)*64, K, &Bl[BUF][(H)*8192], w, lane)

  // prologue: tile0 (4 halves) + A1,B1(tile1); vmcnt(4) -> tile0 landed
  STAGE_A(0, 0, 0); STAGE_B(0, 0, 0); STAGE_A(1, 0, 0); STAGE_B(1, 0, 0);
  if (NT > 1) {
    STAGE_A(0, 1, 1); STAGE_B(0, 1, 1);
    asm volatile("s_waitcnt vmcnt(4)");
  } else {
    asm volatile("s_waitcnt vmcnt(0)");
  }
  __builtin_amdgcn_s_barrier();

  short8 aF[4][2], bFa[2][2], bFb[2][2];

#define LDA(MG, BUF)                                                                   \
  {                                                                                    \
    _Pragma("unroll") for (int mi = 0; mi < 4; ++mi) {                                 \
      const int r = (MG)*128 + wr * 64 + mi * 16 + c16;                                \
      const int sx = ((r >> 2) & 1) << 4;                                              \
      aF[mi][0] = *reinterpret_cast<const short8*>(&Al[BUF][r * 64 + ((g * 8) ^ sx)]); \
      aF[mi][1] = *reinterpret_cast<const short8*>(&Al[BUF][r * 64 + ((32 + g * 8) ^ sx)]); \
    }                                                                                  \
  }
#define LDB(NG, DST, BUF)                                                              \
  {                                                                                    \
    _Pragma("unroll") for (int ni = 0; ni < 2; ++ni) {                                 \
      const int r = (NG)*128 + wc * 32 + ni * 16 + c16;                                \
      const int sx = ((r >> 2) & 1) << 4;                                              \
      DST[ni][0] = *reinterpret_cast<const short8*>(&Bl[BUF][r * 64 + ((g * 8) ^ sx)]); \
      DST[ni][1] = *reinterpret_cast<const short8*>(&Bl[BUF][r * 64 + ((32 + g * 8) ^ sx)]); \
    }                                                                                  \
  }
#define DOMFMA(MG, NG, BF)                                                             \
  __builtin_amdgcn_s_setprio(1);                                                       \
  _Pragma("unroll") for (int mi = 0; mi < 4; ++mi) {                                   \
    _Pragma("unroll") for (int ni = 0; ni < 2; ++ni) {                                 \
      acc[(MG)*4 + mi][(NG)*2 + ni] = __builtin_amdgcn_mfma_f32_16x16x32_bf16(         \
          aF[mi][0], BF[ni][0], acc[(MG)*4 + mi][(NG)*2 + ni], 0, 0, 0);               \
      acc[(MG)*4 + mi][(NG)*2 + ni] = __builtin_amdgcn_mfma_f32_16x16x32_bf16(         \
          aF[mi][1], BF[ni][1], acc[(MG)*4 + mi][(NG)*2 + ni], 0, 0, 0);               \
    }                                                                                  \
  }                                                                                    \
  __builtin_amdgcn_s_setprio(0);

  for (int kt = 0; kt < NT; ++kt) {
    const int buf = kt & 1;
    // ---- phase 1: (mg0, ng0) ----
    LDA(0, buf);
    LDB(0, bFa, buf);
    if (kt + 1 < NT) STAGE_A(1, kt + 1, buf ^ 1);
    __builtin_amdgcn_s_barrier();
    asm volatile("s_waitcnt lgkmcnt(0)");
    DOMFMA(0, 0, bFa);
    __builtin_amdgcn_s_barrier();
    // ---- phase 2: (mg0, ng1) ----
    LDB(1, bFb, buf);
    if (kt + 1 < NT) STAGE_B(1, kt + 1, buf ^ 1);
    __builtin_amdgcn_s_barrier();
    asm volatile("s_waitcnt lgkmcnt(0)");
    DOMFMA(0, 1, bFb);
    __builtin_amdgcn_s_barrier();
    // ---- phase 3: (mg1, ng0) ----
    LDA(1, buf);
    if (kt + 2 < NT) STAGE_A(0, kt + 2, buf);
    __builtin_amdgcn_s_barrier();
    asm volatile("s_waitcnt lgkmcnt(0)");
    DOMFMA(1, 0, bFa);
    __builtin_amdgcn_s_barrier();
    // ---- phase 4: (mg1, ng1) ----
    if (kt + 2 < NT) STAGE_B(0, kt + 2, buf);
    if (kt == NT - 2) {
      asm volatile("s_waitcnt vmcnt(0)");
    } else if (kt < NT - 2) {
      asm volatile("s_waitcnt vmcnt(4)");
    }
    __builtin_amdgcn_s_barrier();
    asm volatile("s_waitcnt lgkmcnt(0)");
    DOMFMA(1, 1, bFb);
    __builtin_amdgcn_s_barrier();
  }
#undef LDA
#undef LDB
#undef DOMFMA
#undef STAGE_A
#undef STAGE_B

  // ---- epilogue ----
#pragma unroll
  for (int mf = 0; mf < 8; ++mf) {
    const int er = row0 + (mf >> 2) * 128 + wr * 64 + (mf & 3) * 16 + g * 4;
#pragma unroll
    for (int nf = 0; nf < 4; ++nf) {
      const int ec = col0 + (nf >> 1) * 128 + wc * 32 + (nf & 1) * 16 + c16;
#pragma unroll
      for (int j = 0; j < 4; ++j) {
        const size_t off = (size_t)(er + j) * ldc + ec;
        if (OUT_BF16)
          ((short*)Cout)[off] = f2bf(acc[mf][nf][j]);
        else
          ((float*)Cout)[off] = acc[mf][nf][j];
      }
    }
  }
}

// ---------------- bf16 MFMA GEMM: C[M][N] = A[M][K] * Bt[N][K]^T (128^2) ----------------
template <int OUT_BF16>
__global__ __launch_bounds__(256) void gemm_kernel(const short* __restrict__ A,
                                                   const short* __restrict__ Bt,
                                                   void* __restrict__ Cout,
                                                   int K, int ldc) {
  __shared__ __align__(16) short Al[2][128 * 32];
  __shared__ __align__(16) short Bl[2][128 * 32];
  const int t = threadIdx.x;
  const int lane = t & 63, w = t >> 6;
  const int wr = w >> 1, wc = w & 1;
  const int g = lane >> 4, c16 = lane & 15;
  const int row0 = blockIdx.y * 128, col0 = blockIdx.x * 128;

  f32x4 acc[4][4];
#pragma unroll
  for (int m = 0; m < 4; ++m)
#pragma unroll
    for (int n = 0; n < 4; ++n) {
      f32x4 z = {0.0f, 0.0f, 0.0f, 0.0f};
      acc[m][n] = z;
    }

  auto stage = [&](int buf, int kt) {
    const int k0 = kt * 32;
#pragma unroll
    for (int i = 0; i < 2; ++i) {
      const int qb = i * 256 + (t & 192); // wave-uniform chunk base
      const int q = qb + lane;
      const int r = q >> 2;
      const int c = (q & 3) ^ ((r >> 1) & 3);
      const short* ga = A + (size_t)(row0 + r) * K + k0 + c * 8;
      const short* gb = Bt + (size_t)(col0 + r) * K + k0 + c * 8;
      __builtin_amdgcn_global_load_lds((const __attribute__((address_space(1))) void*)ga,
                                       (__attribute__((address_space(3))) void*)&Al[buf][qb * 8],
                                       16, 0, 0);
      __builtin_amdgcn_global_load_lds((const __attribute__((address_space(1))) void*)gb,
                                       (__attribute__((address_space(3))) void*)&Bl[buf][qb * 8],
                                       16, 0, 0);
    }
  };

  stage(0, 0);
  __syncthreads();
  const int NK = K >> 5;
  int cur = 0;
  const int rA0 = wr * 64 + c16;
  const int rB0 = wc * 64 + c16;
  for (int kt = 0; kt < NK; ++kt) {
    if (kt + 1 < NK) stage(cur ^ 1, kt + 1);
    short8 aF[4], bF[4];
#pragma unroll
    for (int m = 0; m < 4; ++m) {
      const int r = rA0 + m * 16;
      const int c = g ^ ((r >> 1) & 3);
      aF[m] = *reinterpret_cast<const short8*>(&Al[cur][r * 32 + c * 8]);
    }
#pragma unroll
    for (int n = 0; n < 4; ++n) {
      const int r = rB0 + n * 16;
      const int c = g ^ ((r >> 1) & 3);
      bF[n] = *reinterpret_cast<const short8*>(&Bl[cur][r * 32 + c * 8]);
    }
#pragma unroll
    for (int m = 0; m < 4; ++m)
#pragma unroll
      for (int n = 0; n < 4; ++n)
        acc[m][n] = __builtin_amdgcn_mfma_f32_16x16x32_bf16(aF[m], bF[n], acc[m][n], 0, 0, 0);
    __syncthreads();
    cur ^= 1;
  }

  const int er = row0 + wr * 64 + g * 4;
  const int ec = col0 + wc * 64 + c16;
#pragma unroll
  for (int m = 0; m < 4; ++m)
#pragma unroll
    for (int n = 0; n < 4; ++n)
#pragma unroll
      for (int j = 0; j < 4; ++j) {
        const size_t off = (size_t)(er + m * 16 + j) * ldc + ec + n * 16;
        if (OUT_BF16)
          ((short*)Cout)[off] = f2bf(acc[m][n][j]);
        else
          ((float*)Cout)[off] = acc[m][n][j];
      }
}

// ---------------- fused causal attention with trigram geo bias ----------------
// Swapped-QK^T structure: compute mfma(K, Q) so each lane holds a full P row
// (q = c16) in registers. Softmax = in-register + 2 shfl_xor. P_lds deleted;
// PV A-fragments rebuilt via 16 shfl + 8 selects. exp2-domain softmax.
// 512 blocks LPT-descending, bh clustered 4-per-XCD, K/V double-buffered.
__global__ __launch_bounds__(256) void attn_kernel(const short* __restrict__ qkvb,
                                                   const short* __restrict__ vT,
                                                   const float* __restrict__ head_scales,
                                                   const float* __restrict__ hdirs,
                                                   const float* __restrict__ kproj,
                                                   short* __restrict__ attnb) {
  __shared__ __align__(16) short Kl[2][64 * 128];
  __shared__ __align__(16) short Vl[2][128 * 64];
  __shared__ float kp_lds[2][64];

  const int bid = blockIdx.x;                       // 0..511
  const int bh = (bid & 7) * 4 + ((bid >> 3) & 3);  // 4 bh per XCD
  const int qt = 15 - (bid >> 5);                   // big tiles dispatched first
  const int b = bh >> 3, h = bh & 7;
  const int t = threadIdx.x, lane = t & 63, w = t >> 6;
  const int g = lane >> 4, c16 = lane & 15;
  const int q0w = qt * 64 + w * 16;
  const int q_abs = q0w + c16; // this lane's q row

  const short* qbase = qkvb + (size_t)(b * 1024) * 3072 + h * 128;
  const short* kbase = qbase + 1024;
  const short* vtb = vT + (size_t)bh * 128 * 1024;
  const float* kp = kproj + bh * 1024;

  const float LOG2E = 1.44269504088896f;
  const float scale2 = 0.08838834764831845f * 1.44269504088896f; // /sqrt(128)*log2e

  // Q fragments (B-operand): col = c16 (q row), k = kk*32 + g*8 .. +7
  short8 aQ[4];
  float hqp; // hs * qproj(row c16) * log2e
  {
    const short* qr = qbase + (size_t)(q0w + c16) * 3072;
#pragma unroll
    for (int kk = 0; kk < 4; ++kk)
      aQ[kk] = *reinterpret_cast<const short8*>(qr + kk * 32 + g * 8);
    const float hs = head_scales[h];
    hqp = hs * LOG2E *
          (b2f(qr[0]) * hdirs[h * 3] + b2f(qr[1]) * hdirs[h * 3 + 1] + b2f(qr[2]) * hdirs[h * 3 + 2]);
  }

  float m_s = -1e30f, l_s = 0.0f; // per q-row (= c16), replicated across g
  f32x4 accO[8];
#pragma unroll
  for (int d = 0; d < 8; ++d) {
    f32x4 z = {0.0f, 0.0f, 0.0f, 0.0f};
    accO[d] = z;
  }

  auto stageKV = [&](int buf, int kvt) {
    const int kv0 = kvt * 64;
#pragma unroll
    for (int i = 0; i < 4; ++i) {
      const int s = w * 4 + i;
      {
        const int r = s * 4 + g;            // kv row
        const int c = c16 ^ (r & 7);        // global 16B chunk (16/row)
        const short* ga = kbase + (size_t)(kv0 + r) * 3072 + c * 8;
        __builtin_amdgcn_global_load_lds((const __attribute__((address_space(1))) void*)ga,
                                         (__attribute__((address_space(3))) void*)&Kl[buf][s * 512],
                                         16, 0, 0);
      }
      {
        const int r = s * 8 + (lane >> 3);  // d row
        const int c = (lane & 7) ^ (r & 7); // global 16B chunk (8/row)
        const short* ga = vtb + (size_t)r * 1024 + kv0 + c * 8;
        __builtin_amdgcn_global_load_lds((const __attribute__((address_space(1))) void*)ga,
                                         (__attribute__((address_space(3))) void*)&Vl[buf][s * 512],
                                         16, 0, 0);
      }
    }
    if (lane < 16) kp_lds[buf][w * 16 + lane] = kp[kv0 + w * 16 + lane];
  };

  const int nkv = qt + 1;
  stageKV(0, 0);
  __syncthreads();
  int cur = 0;
  for (int kvt = 0; kvt < nkv; ++kvt) {
    const int kv0 = kvt * 64;
    if (kvt + 1 < nkv) stageKV(cur ^ 1, kvt + 1); // prefetch overlaps compute
    const short* Kc = Kl[cur];
    const short* Vc = Vl[cur];
    const float* kpc = kp_lds[cur];

    // ---- swapped QK^T: p[n][j] = P[k = n*16+g*4+j][q = c16] ----
    float p[4][4];
#pragma unroll
    for (int n = 0; n < 4; ++n) {
      f32x4 s4 = {0.0f, 0.0f, 0.0f, 0.0f};
      const int r = n * 16 + c16; // kv row within tile (A-operand row)
#pragma unroll
      for (int kk = 0; kk < 4; ++kk) {
        const int cch = (kk * 4 + g) ^ (r & 7);
        short8 bK = *reinterpret_cast<const short8*>(&Kc[r * 128 + cch * 8]);
        s4 = __builtin_amdgcn_mfma_f32_16x16x32_bf16(bK, aQ[kk], s4, 0, 0, 0);
      }
#pragma unroll
      for (int j = 0; j < 4; ++j) {
        const int kloc = n * 16 + g * 4 + j;
        const float v = s4[j] * scale2 + hqp * kpc[kloc];
        p[n][j] = (kv0 + kloc <= q_abs) ? v : -1e30f;
      }
    }

    // ---- row max: in-register tree + 2 shfl_xor ----
    float mx;
    {
      float a0 = fmaxf(fmaxf(p[0][0], p[0][1]), fmaxf(p[0][2], p[0][3]));
      float a1 = fmaxf(fmaxf(p[1][0], p[1][1]), fmaxf(p[1][2], p[1][3]));
      float a2 = fmaxf(fmaxf(p[2][0], p[2][1]), fmaxf(p[2][2], p[2][3]));
      float a3 = fmaxf(fmaxf(p[3][0], p[3][1]), fmaxf(p[3][2], p[3][3]));
      mx = fmaxf(fmaxf(a0, a1), fmaxf(a2, a3));
      mx = fmaxf(mx, __shfl_xor(mx, 16, 64));
      mx = fmaxf(mx, __shfl_xor(mx, 32, 64));
    }

    // ---- defer-max (THR = 8 nats = 11.54 in log2 domain) ----
    if (__any(mx - m_s > 11.54f)) {
      const float mn = fmaxf(m_s, mx);
      const float alpha = exp2f(m_s - mn);
      m_s = mn;
      l_s *= alpha;
      float aO[4];
#pragma unroll
      for (int j = 0; j < 4; ++j) aO[j] = __shfl(alpha, g * 4 + j, 64);
#pragma unroll
      for (int d = 0; d < 8; ++d)
#pragma unroll
        for (int j = 0; j < 4; ++j) accO[d][j] *= aO[j];
    }

    // ---- exp2 + row sum (tree + 2 shfl_xor) ----
    float s01 = 0.0f, s23 = 0.0f;
#pragma unroll
    for (int n = 0; n < 4; ++n) {
      float e0 = exp2f(p[n][0] - m_s), e1 = exp2f(p[n][1] - m_s);
      float e2 = exp2f(p[n][2] - m_s), e3 = exp2f(p[n][3] - m_s);
      p[n][0] = e0; p[n][1] = e1; p[n][2] = e2; p[n][3] = e3;
      if (n < 2) s01 += (e0 + e1) + (e2 + e3); else s23 += (e0 + e1) + (e2 + e3);
    }
    float sum = s01 + s23;
    sum += __shfl_xor(sum, 16, 64);
    sum += __shfl_xor(sum, 32, 64);
    l_s += sum;

    // ---- pack to bf16 pairs: pk[n][u] = {k = n*16+g*4+2u, +1} ----
    uint32_t pk[4][2];
#pragma unroll
    for (int n = 0; n < 4; ++n) {
      pk[n][0] = pack2bf(p[n][0], p[n][1]);
      pk[n][1] = pack2bf(p[n][2], p[n][3]);
    }

    // ---- redistribute to PV A-fragments: aP[kk] = P[q=c16][k=kk*32+g*8..+7] ----
    union { uint32_t d[4]; short8 s; } aPu[2];
#pragma unroll
    for (int kk = 0; kk < 2; ++kk)
#pragma unroll
      for (int wd = 0; wd < 4; ++wd) {
        const int src = (2 * (g & 1) + (wd >> 1)) * 16 + c16;
        const uint32_t v0 = (uint32_t)__shfl((int)pk[kk * 2][wd & 1], src, 64);
        const uint32_t v1 = (uint32_t)__shfl((int)pk[kk * 2 + 1][wd & 1], src, 64);
        aPu[kk].d[wd] = (g >= 2) ? v1 : v0;
      }

    // ---- PV (unchanged layout: D row = q = g*4+j, col = d = c16) ----
#pragma unroll
    for (int dt = 0; dt < 8; ++dt) {
      const int r = dt * 16 + c16; // d row in Vl
#pragma unroll
      for (int kk = 0; kk < 2; ++kk) {
        const int cch = (kk * 4 + g) ^ (r & 7);
        short8 bV = *reinterpret_cast<const short8*>(&Vc[r * 64 + cch * 8]);
        accO[dt] = __builtin_amdgcn_mfma_f32_16x16x32_bf16(aPu[kk].s, bV, accO[dt], 0, 0, 0);
      }
    }
    __syncthreads(); // next buffer staged + all waves done reading cur
    cur ^= 1;
  }

  // ---- epilogue: fetch per-row 1/l via shfl, store bf16 [B,T,D] ----
  float linv[4];
#pragma unroll
  for (int j = 0; j < 4; ++j) linv[j] = 1.0f / __shfl(l_s, g * 4 + j, 64);
#pragma unroll
  for (int j = 0; j < 4; ++j) {
    const size_t rowoff = (size_t)(b * 1024 + q0w + g * 4 + j) * 1024 + h * 128;
#pragma unroll
    for (int dt = 0; dt < 8; ++dt)
      attnb[rowoff + dt * 16 + c16] = f2bf(accO[dt][j] * linv[j]);
  }
}

extern "C" void kernel_launch(void* const* d_in, const int* in_sizes, int n_in,
                              void* d_out, int out_size, void* d_ws, size_t ws_size,
                              hipStream_t stream) {
  const float* x = (const float*)d_in[0];
  const float* Wqkv = (const float*)d_in[1];
  const float* Wout = (const float*)d_in[2];
  const float* hscale = (const float*)d_in[3];
  const float* hdirs = (const float*)d_in[4];
  float* out = (float*)d_out;

  char* ws = (char*)d_ws;
  short* xb = (short*)(ws);                                  // 8 MB (dead after gemm1)
  short* wqkvT = (short*)(ws + (size_t)8 * 1024 * 1024);     // 6 MB
  short* woutT = (short*)(ws + (size_t)14 * 1024 * 1024);    // 2 MB
  short* qkvb = (short*)(ws + (size_t)16 * 1024 * 1024);     // 24 MB
  short* vT = (short*)(ws + (size_t)40 * 1024 * 1024);       // 8 MB
  short* attnb = (short*)(ws + (size_t)48 * 1024 * 1024);    // 8 MB
  float* kproj = (float*)(ws);                               // 128 KB, reuses dead xb region

  cvt_kernel<<<2048, 256, 0, stream>>>(x, xb, (4 * 1024 * 1024) / 4);
  tcvt_kernel<<<dim3(96, 32), 256, 0, stream>>>(Wqkv, wqkvT, 1024, 3072);
  tcvt_kernel<<<dim3(32, 32), 256, 0, stream>>>(Wout, woutT, 1024, 1024);
  // gemm1: M=4096 x N=3072 x K=1024, 256^2 8-phase, grid 16*12=192 (192%8==0)
  gemm256_kernel<1><<<192, 512, 0, stream>>>(xb, wqkvT, (void*)qkvb, 1024, 3072, 12);
  kproj_kernel<<<128, 256, 0, stream>>>(qkvb, hdirs, kproj);
  vtrans_kernel<<<dim3(16, 16, 4), 256, 0, stream>>>(qkvb, vT);
  attn_kernel<<<512, 256, 0, stream>>>(qkvb, vT, hscale, hdirs, kproj, attnb);
  gemm_kernel<0><<<dim3(8, 32), 256, 0, stream>>>(attnb, woutT, out, 1024, 1024);
}

// Round 7
// 122.775 us; speedup vs baseline: 1.0235x; 1.0235x over previous
//
#include <hip/hip_runtime.h>
#include <stdint.h>

typedef __attribute__((ext_vector_type(8))) short short8;
typedef __attribute__((ext_vector_type(4))) short short4v;
typedef __attribute__((ext_vector_type(4))) float f32x4;

__device__ __forceinline__ short f2bf(float x) {
  union { float f; uint32_t u; } c; c.f = x;
  uint32_t r = (c.u + 0x7FFFu + ((c.u >> 16) & 1u)) >> 16;
  return (short)r;
}
__device__ __forceinline__ float b2f(short s) {
  union { uint32_t u; float f; } c; c.u = ((uint32_t)(uint16_t)s) << 16;
  return c.f;
}
__device__ __forceinline__ uint32_t pack2bf(float lo, float hi) {
  return ((uint32_t)(uint16_t)f2bf(hi) << 16) | (uint32_t)(uint16_t)f2bf(lo);
}

// ---------------- fp32 -> bf16 convert (vectorized) ----------------
__global__ __launch_bounds__(256) void cvt_kernel(const float* __restrict__ in,
                                                  short* __restrict__ out, int n4) {
  int i = blockIdx.x * 256 + threadIdx.x;
  const int stride = gridDim.x * 256;
  for (; i < n4; i += stride) {
    float4 v = reinterpret_cast<const float4*>(in)[i];
    short4v o;
    o.x = f2bf(v.x); o.y = f2bf(v.y); o.z = f2bf(v.z); o.w = f2bf(v.w);
    reinterpret_cast<short4v*>(out)[i] = o;
  }
}

// ------------- fp32 [K][N] -> bf16 [N][K] transpose-convert -------------
__global__ __launch_bounds__(256) void tcvt_kernel(const float* __restrict__ in,
                                                   short* __restrict__ out, int K, int N) {
  __shared__ __align__(16) short tile[32][33];
  const int nb = blockIdx.x * 32, kb = blockIdx.y * 32;
  const int tx = threadIdx.x & 31, ty = threadIdx.x >> 5; // 32 x 8
#pragma unroll
  for (int i = 0; i < 32; i += 8)
    tile[ty + i][tx] = f2bf(in[(size_t)(kb + ty + i) * N + nb + tx]);
  __syncthreads();
#pragma unroll
  for (int i = 0; i < 32; i += 8)
    out[(size_t)(nb + ty + i) * K + kb + tx] = tile[tx][ty + i];
}

// ------------- bf16 V-region transpose: qkv[b][kv][2048+c] -> vT[b][c][kv] -------------
__global__ __launch_bounds__(256) void vtrans_kernel(const short* __restrict__ qkvb,
                                                     short* __restrict__ vT) {
  __shared__ __align__(16) short tile[64][65];
  const int b = blockIdx.z;
  const int kv0 = blockIdx.x * 64, c0 = blockIdx.y * 64;
  const int tx = threadIdx.x & 15, ty = threadIdx.x >> 4; // 16 x 16
  const short* src = qkvb + (size_t)(b * 1024) * 3072 + 2048;
#pragma unroll
  for (int i = 0; i < 64; i += 16) {
    int r = ty + i;
#pragma unroll
    for (int j = 0; j < 4; ++j)
      tile[r][tx * 4 + j] = src[(size_t)(kv0 + r) * 3072 + c0 + tx * 4 + j];
  }
  __syncthreads();
  short* dst = vT + (size_t)b * 1024 * 1024;
#pragma unroll
  for (int i = 0; i < 64; i += 16) {
    int cc = ty + i;
#pragma unroll
    for (int j = 0; j < 4; ++j)
      dst[(size_t)(c0 + cc) * 1024 + kv0 + tx * 4 + j] = tile[tx * 4 + j][cc];
  }
}

// ------------- k-projection precompute: kproj[bh][t] = dot(K[b,t,h,0:3], dir_h) -------------
__global__ __launch_bounds__(256) void kproj_kernel(const short* __restrict__ qkvb,
                                                    const float* __restrict__ hdirs,
                                                    float* __restrict__ kproj) {
  const int i = blockIdx.x * 256 + threadIdx.x; // over 32*1024
  const int bh = i >> 10, tt = i & 1023;
  const int b = bh >> 3, h = bh & 7;
  const float d0 = hdirs[h * 3], d1 = hdirs[h * 3 + 1], d2 = hdirs[h * 3 + 2];
  const short* kr = qkvb + (size_t)(b * 1024 + tt) * 3072 + 1024 + h * 128;
  kproj[i] = b2f(kr[0]) * d0 + b2f(kr[1]) * d1 + b2f(kr[2]) * d2;
}

// ================= 256x256 BK=64 8-phase GEMM (T1+T2+T3/T4+T5) =================
// C[M][N] = A[M][K] * Bt[N][K]^T, 512 threads = 8 waves (wr 0..1 x wc 0..3).
// LDS 128KB: Al/Bl [2 bufs][256][64] bf16. 3-bit row XOR swizzle:
//   LDS[r][slot s] = G[r][s ^ (r&7)]  (slot = 16B chunk, 8 per row)
// applied via inverse-swizzled GLOBAL source (linear glds dest, rr&7 == lane>>3)
// and XOR'd ds_read cols. Phases: (mg0,ng0),(mg0,ng1),(mg1,ng0),(mg1,ng1);
// region-freed staging; vmcnt(4) once per K-tile (never 0 mid-loop).
__device__ __forceinline__ void stage_half256(const short* __restrict__ gsrc,
                                              int K, short* lds_half,
                                              int w, int lane) {
#pragma unroll
  for (int i = 0; i < 2; ++i) {
    const int chunk = w * 2 + i;                 // 16 x 1KB chunks per half
    const int rr = chunk * 8 + (lane >> 3);      // row within half (0..127), rr&7 == lane>>3
    const int cc = ((lane & 7) ^ (lane >> 3)) * 8; // inverse-swizzled global 16B slot
    const short* ga = gsrc + (size_t)rr * K + cc;
    __builtin_amdgcn_global_load_lds((const __attribute__((address_space(1))) void*)ga,
                                     (__attribute__((address_space(3))) void*)(lds_half + chunk * 512),
                                     16, 0, 0);
  }
}

template <int OUT_BF16>
__global__ __launch_bounds__(512, 2) void gemm256_kernel(const short* __restrict__ A,
                                                         const short* __restrict__ Bt,
                                                         void* __restrict__ Cout,
                                                         int K, int ldc, int nbx) {
  __shared__ __align__(16) short Al[2][256 * 64];
  __shared__ __align__(16) short Bl[2][256 * 64];
  const int t = threadIdx.x;
  const int lane = t & 63, w = t >> 6;
  const int wr = w >> 2, wc = w & 3;
  const int g = lane >> 4, c16 = lane & 15;
  // XCD-aware bijective swizzle (grid % 8 == 0 guaranteed by launch)
  const int nwg = gridDim.x;
  const int swz = (blockIdx.x & 7) * (nwg >> 3) + (blockIdx.x >> 3);
  const int row0 = (swz / nbx) * 256, col0 = (swz % nbx) * 256;

  f32x4 acc[8][4];
#pragma unroll
  for (int m = 0; m < 8; ++m)
#pragma unroll
    for (int n = 0; n < 4; ++n) {
      f32x4 z = {0.0f, 0.0f, 0.0f, 0.0f};
      acc[m][n] = z;
    }

  const int NT = K >> 6;
#define STAGE_A(H, KT, BUF) stage_half256(A + (size_t)(row0 + (H)*128) * K + (KT)*64, K, &Al[BUF][(H)*8192], w, lane)
#define STAGE_B(H, KT, BUF) stage_half256(Bt + (size_t)(col0 + (H)*128) * K + (KT)*64, K, &Bl[BUF][(H)*8192], w, lane)

  // prologue: tile0 (4 halves) + A1,B1(tile1); vmcnt(4) -> tile0 landed
  STAGE_A(0, 0, 0); STAGE_B(0, 0, 0); STAGE_A(1, 0, 0); STAGE_B(1, 0, 0);
  if (NT > 1) {
    STAGE_A(0, 1, 1); STAGE_B(0, 1, 1);
    asm volatile("s_waitcnt vmcnt(4)");
  } else {
    asm volatile("s_waitcnt vmcnt(0)");
  }
  __builtin_amdgcn_s_barrier();

  short8 aF[4][2], bFa[2][2], bFb[2][2];

#define LDA(MG, BUF)                                                                        \
  {                                                                                         \
    _Pragma("unroll") for (int mi = 0; mi < 4; ++mi) {                                      \
      const int r = (MG)*128 + wr * 64 + mi * 16 + c16;                                     \
      const int rx = r & 7;                                                                 \
      aF[mi][0] = *reinterpret_cast<const short8*>(&Al[BUF][r * 64 + ((g ^ rx) * 8)]);      \
      aF[mi][1] = *reinterpret_cast<const short8*>(&Al[BUF][r * 64 + (((4 + g) ^ rx) * 8)]); \
    }                                                                                       \
  }
#define LDB(NG, DST, BUF)                                                                   \
  {                                                                                         \
    _Pragma("unroll") for (int ni = 0; ni < 2; ++ni) {                                      \
      const int r = (NG)*128 + wc * 32 + ni * 16 + c16;                                     \
      const int rx = r & 7;                                                                 \
      DST[ni][0] = *reinterpret_cast<const short8*>(&Bl[BUF][r * 64 + ((g ^ rx) * 8)]);     \
      DST[ni][1] = *reinterpret_cast<const short8*>(&Bl[BUF][r * 64 + (((4 + g) ^ rx) * 8)]); \
    }                                                                                       \
  }
#define DOMFMA(MG, NG, BF)                                                             \
  __builtin_amdgcn_s_setprio(1);                                                       \
  _Pragma("unroll") for (int mi = 0; mi < 4; ++mi) {                                   \
    _Pragma("unroll") for (int ni = 0; ni < 2; ++ni) {                                 \
      acc[(MG)*4 + mi][(NG)*2 + ni] = __builtin_amdgcn_mfma_f32_16x16x32_bf16(         \
          aF[mi][0], BF[ni][0], acc[(MG)*4 + mi][(NG)*2 + ni], 0, 0, 0);               \
      acc[(MG)*4 + mi][(NG)*2 + ni] = __builtin_amdgcn_mfma_f32_16x16x32_bf16(         \
          aF[mi][1], BF[ni][1], acc[(MG)*4 + mi][(NG)*2 + ni], 0, 0, 0);               \
    }                                                                                  \
  }                                                                                    \
  __builtin_amdgcn_s_setprio(0);

  for (int kt = 0; kt < NT; ++kt) {
    const int buf = kt & 1;
    // ---- phase 1: (mg0, ng0) ----
    LDA(0, buf);
    LDB(0, bFa, buf);
    if (kt + 1 < NT) STAGE_A(1, kt + 1, buf ^ 1);
    __builtin_amdgcn_s_barrier();
    asm volatile("s_waitcnt lgkmcnt(0)");
    DOMFMA(0, 0, bFa);
    __builtin_amdgcn_s_barrier();
    // ---- phase 2: (mg0, ng1) ----
    LDB(1, bFb, buf);
    if (kt + 1 < NT) STAGE_B(1, kt + 1, buf ^ 1);
    __builtin_amdgcn_s_barrier();
    asm volatile("s_waitcnt lgkmcnt(0)");
    DOMFMA(0, 1, bFb);
    __builtin_amdgcn_s_barrier();
    // ---- phase 3: (mg1, ng0) ----
    LDA(1, buf);
    if (kt + 2 < NT) STAGE_A(0, kt + 2, buf);
    __builtin_amdgcn_s_barrier();
    asm volatile("s_waitcnt lgkmcnt(0)");
    DOMFMA(1, 0, bFa);
    __builtin_amdgcn_s_barrier();
    // ---- phase 4: (mg1, ng1) ----
    if (kt + 2 < NT) STAGE_B(0, kt + 2, buf);
    if (kt == NT - 2) {
      asm volatile("s_waitcnt vmcnt(0)");
    } else if (kt < NT - 2) {
      asm volatile("s_waitcnt vmcnt(4)");
    }
    __builtin_amdgcn_s_barrier();
    asm volatile("s_waitcnt lgkmcnt(0)");
    DOMFMA(1, 1, bFb);
    __builtin_amdgcn_s_barrier();
  }
#undef LDA
#undef LDB
#undef DOMFMA
#undef STAGE_A
#undef STAGE_B

  // ---- epilogue ----
#pragma unroll
  for (int mf = 0; mf < 8; ++mf) {
    const int er = row0 + (mf >> 2) * 128 + wr * 64 + (mf & 3) * 16 + g * 4;
#pragma unroll
    for (int nf = 0; nf < 4; ++nf) {
      const int ec = col0 + (nf >> 1) * 128 + wc * 32 + (nf & 1) * 16 + c16;
#pragma unroll
      for (int j = 0; j < 4; ++j) {
        const size_t off = (size_t)(er + j) * ldc + ec;
        if (OUT_BF16)
          ((short*)Cout)[off] = f2bf(acc[mf][nf][j]);
        else
          ((float*)Cout)[off] = acc[mf][nf][j];
      }
    }
  }
}

// ---------------- bf16 MFMA GEMM: C[M][N] = A[M][K] * Bt[N][K]^T (128^2) ----------------
template <int OUT_BF16>
__global__ __launch_bounds__(256) void gemm_kernel(const short* __restrict__ A,
                                                   const short* __restrict__ Bt,
                                                   void* __restrict__ Cout,
                                                   int K, int ldc) {
  __shared__ __align__(16) short Al[2][128 * 32];
  __shared__ __align__(16) short Bl[2][128 * 32];
  const int t = threadIdx.x;
  const int lane = t & 63, w = t >> 6;
  const int wr = w >> 1, wc = w & 1;
  const int g = lane >> 4, c16 = lane & 15;
  const int row0 = blockIdx.y * 128, col0 = blockIdx.x * 128;

  f32x4 acc[4][4];
#pragma unroll
  for (int m = 0; m < 4; ++m)
#pragma unroll
    for (int n = 0; n < 4; ++n) {
      f32x4 z = {0.0f, 0.0f, 0.0f, 0.0f};
      acc[m][n] = z;
    }

  auto stage = [&](int buf, int kt) {
    const int k0 = kt * 32;
#pragma unroll
    for (int i = 0; i < 2; ++i) {
      const int qb = i * 256 + (t & 192); // wave-uniform chunk base
      const int q = qb + lane;
      const int r = q >> 2;
      const int c = (q & 3) ^ ((r >> 1) & 3);
      const short* ga = A + (size_t)(row0 + r) * K + k0 + c * 8;
      const short* gb = Bt + (size_t)(col0 + r) * K + k0 + c * 8;
      __builtin_amdgcn_global_load_lds((const __attribute__((address_space(1))) void*)ga,
                                       (__attribute__((address_space(3))) void*)&Al[buf][qb * 8],
                                       16, 0, 0);
      __builtin_amdgcn_global_load_lds((const __attribute__((address_space(1))) void*)gb,
                                       (__attribute__((address_space(3))) void*)&Bl[buf][qb * 8],
                                       16, 0, 0);
    }
  };

  stage(0, 0);
  __syncthreads();
  const int NK = K >> 5;
  int cur = 0;
  const int rA0 = wr * 64 + c16;
  const int rB0 = wc * 64 + c16;
  for (int kt = 0; kt < NK; ++kt) {
    if (kt + 1 < NK) stage(cur ^ 1, kt + 1);
    short8 aF[4], bF[4];
#pragma unroll
    for (int m = 0; m < 4; ++m) {
      const int r = rA0 + m * 16;
      const int c = g ^ ((r >> 1) & 3);
      aF[m] = *reinterpret_cast<const short8*>(&Al[cur][r * 32 + c * 8]);
    }
#pragma unroll
    for (int n = 0; n < 4; ++n) {
      const int r = rB0 + n * 16;
      const int c = g ^ ((r >> 1) & 3);
      bF[n] = *reinterpret_cast<const short8*>(&Bl[cur][r * 32 + c * 8]);
    }
#pragma unroll
    for (int m = 0; m < 4; ++m)
#pragma unroll
      for (int n = 0; n < 4; ++n)
        acc[m][n] = __builtin_amdgcn_mfma_f32_16x16x32_bf16(aF[m], bF[n], acc[m][n], 0, 0, 0);
    __syncthreads();
    cur ^= 1;
  }

  const int er = row0 + wr * 64 + g * 4;
  const int ec = col0 + wc * 64 + c16;
#pragma unroll
  for (int m = 0; m < 4; ++m)
#pragma unroll
    for (int n = 0; n < 4; ++n)
#pragma unroll
      for (int j = 0; j < 4; ++j) {
        const size_t off = (size_t)(er + m * 16 + j) * ldc + ec + n * 16;
        if (OUT_BF16)
          ((short*)Cout)[off] = f2bf(acc[m][n][j]);
        else
          ((float*)Cout)[off] = acc[m][n][j];
      }
}

// ---------------- fused causal attention with trigram geo bias ----------------
// Swapped-QK^T structure: compute mfma(K, Q) so each lane holds a full P row
// (q = c16) in registers. Softmax = in-register + 2 shfl_xor. P_lds deleted;
// PV A-fragments rebuilt via 16 shfl + 8 selects. exp2-domain softmax.
// 512 blocks LPT-descending, bh clustered 4-per-XCD, K/V double-buffered.
__global__ __launch_bounds__(256) void attn_kernel(const short* __restrict__ qkvb,
                                                   const short* __restrict__ vT,
                                                   const float* __restrict__ head_scales,
                                                   const float* __restrict__ hdirs,
                                                   const float* __restrict__ kproj,
                                                   short* __restrict__ attnb) {
  __shared__ __align__(16) short Kl[2][64 * 128];
  __shared__ __align__(16) short Vl[2][128 * 64];
  __shared__ float kp_lds[2][64];

  const int bid = blockIdx.x;                       // 0..511
  const int bh = (bid & 7) * 4 + ((bid >> 3) & 3);  // 4 bh per XCD
  const int qt = 15 - (bid >> 5);                   // big tiles dispatched first
  const int b = bh >> 3, h = bh & 7;
  const int t = threadIdx.x, lane = t & 63, w = t >> 6;
  const int g = lane >> 4, c16 = lane & 15;
  const int q0w = qt * 64 + w * 16;
  const int q_abs = q0w + c16; // this lane's q row

  const short* qbase = qkvb + (size_t)(b * 1024) * 3072 + h * 128;
  const short* kbase = qbase + 1024;
  const short* vtb = vT + (size_t)bh * 128 * 1024;
  const float* kp = kproj + bh * 1024;

  const float LOG2E = 1.44269504088896f;
  const float scale2 = 0.08838834764831845f * 1.44269504088896f; // /sqrt(128)*log2e

  // Q fragments (B-operand): col = c16 (q row), k = kk*32 + g*8 .. +7
  short8 aQ[4];
  float hqp; // hs * qproj(row c16) * log2e
  {
    const short* qr = qbase + (size_t)(q0w + c16) * 3072;
#pragma unroll
    for (int kk = 0; kk < 4; ++kk)
      aQ[kk] = *reinterpret_cast<const short8*>(qr + kk * 32 + g * 8);
    const float hs = head_scales[h];
    hqp = hs * LOG2E *
          (b2f(qr[0]) * hdirs[h * 3] + b2f(qr[1]) * hdirs[h * 3 + 1] + b2f(qr[2]) * hdirs[h * 3 + 2]);
  }

  float m_s = -1e30f, l_s = 0.0f; // per q-row (= c16), replicated across g
  f32x4 accO[8];
#pragma unroll
  for (int d = 0; d < 8; ++d) {
    f32x4 z = {0.0f, 0.0f, 0.0f, 0.0f};
    accO[d] = z;
  }

  auto stageKV = [&](int buf, int kvt) {
    const int kv0 = kvt * 64;
#pragma unroll
    for (int i = 0; i < 4; ++i) {
      const int s = w * 4 + i;
      {
        const int r = s * 4 + g;            // kv row
        const int c = c16 ^ (r & 7);        // global 16B chunk (16/row)
        const short* ga = kbase + (size_t)(kv0 + r) * 3072 + c * 8;
        __builtin_amdgcn_global_load_lds((const __attribute__((address_space(1))) void*)ga,
                                         (__attribute__((address_space(3))) void*)&Kl[buf][s * 512],
                                         16, 0, 0);
      }
      {
        const int r = s * 8 + (lane >> 3);  // d row
        const int c = (lane & 7) ^ (r & 7); // global 16B chunk (8/row)
        const short* ga = vtb + (size_t)r * 1024 + kv0 + c * 8;
        __builtin_amdgcn_global_load_lds((const __attribute__((address_space(1))) void*)ga,
                                         (__attribute__((address_space(3))) void*)&Vl[buf][s * 512],
                                         16, 0, 0);
      }
    }
    if (lane < 16) kp_lds[buf][w * 16 + lane] = kp[kv0 + w * 16 + lane];
  };

  const int nkv = qt + 1;
  stageKV(0, 0);
  __syncthreads();
  int cur = 0;
  for (int kvt = 0; kvt < nkv; ++kvt) {
    const int kv0 = kvt * 64;
    if (kvt + 1 < nkv) stageKV(cur ^ 1, kvt + 1); // prefetch overlaps compute
    const short* Kc = Kl[cur];
    const short* Vc = Vl[cur];
    const float* kpc = kp_lds[cur];

    // ---- swapped QK^T: p[n][j] = P[k = n*16+g*4+j][q = c16] ----
    float p[4][4];
#pragma unroll
    for (int n = 0; n < 4; ++n) {
      f32x4 s4 = {0.0f, 0.0f, 0.0f, 0.0f};
      const int r = n * 16 + c16; // kv row within tile (A-operand row)
#pragma unroll
      for (int kk = 0; kk < 4; ++kk) {
        const int cch = (kk * 4 + g) ^ (r & 7);
        short8 bK = *reinterpret_cast<const short8*>(&Kc[r * 128 + cch * 8]);
        s4 = __builtin_amdgcn_mfma_f32_16x16x32_bf16(bK, aQ[kk], s4, 0, 0, 0);
      }
#pragma unroll
      for (int j = 0; j < 4; ++j) {
        const int kloc = n * 16 + g * 4 + j;
        const float v = s4[j] * scale2 + hqp * kpc[kloc];
        p[n][j] = (kv0 + kloc <= q_abs) ? v : -1e30f;
      }
    }

    // ---- row max: in-register tree + 2 shfl_xor ----
    float mx;
    {
      float a0 = fmaxf(fmaxf(p[0][0], p[0][1]), fmaxf(p[0][2], p[0][3]));
      float a1 = fmaxf(fmaxf(p[1][0], p[1][1]), fmaxf(p[1][2], p[1][3]));
      float a2 = fmaxf(fmaxf(p[2][0], p[2][1]), fmaxf(p[2][2], p[2][3]));
      float a3 = fmaxf(fmaxf(p[3][0], p[3][1]), fmaxf(p[3][2], p[3][3]));
      mx = fmaxf(fmaxf(a0, a1), fmaxf(a2, a3));
      mx = fmaxf(mx, __shfl_xor(mx, 16, 64));
      mx = fmaxf(mx, __shfl_xor(mx, 32, 64));
    }

    // ---- defer-max (THR = 8 nats = 11.54 in log2 domain) ----
    if (__any(mx - m_s > 11.54f)) {
      const float mn = fmaxf(m_s, mx);
      const float alpha = exp2f(m_s - mn);
      m_s = mn;
      l_s *= alpha;
      float aO[4];
#pragma unroll
      for (int j = 0; j < 4; ++j) aO[j] = __shfl(alpha, g * 4 + j, 64);
#pragma unroll
      for (int d = 0; d < 8; ++d)
#pragma unroll
        for (int j = 0; j < 4; ++j) accO[d][j] *= aO[j];
    }

    // ---- exp2 + row sum (tree + 2 shfl_xor) ----
    float s01 = 0.0f, s23 = 0.0f;
#pragma unroll
    for (int n = 0; n < 4; ++n) {
      float e0 = exp2f(p[n][0] - m_s), e1 = exp2f(p[n][1] - m_s);
      float e2 = exp2f(p[n][2] - m_s), e3 = exp2f(p[n][3] - m_s);
      p[n][0] = e0; p[n][1] = e1; p[n][2] = e2; p[n][3] = e3;
      if (n < 2) s01 += (e0 + e1) + (e2 + e3); else s23 += (e0 + e1) + (e2 + e3);
    }
    float sum = s01 + s23;
    sum += __shfl_xor(sum, 16, 64);
    sum += __shfl_xor(sum, 32, 64);
    l_s += sum;

    // ---- pack to bf16 pairs: pk[n][u] = {k = n*16+g*4+2u, +1} ----
    uint32_t pk[4][2];
#pragma unroll
    for (int n = 0; n < 4; ++n) {
      pk[n][0] = pack2bf(p[n][0], p[n][1]);
      pk[n][1] = pack2bf(p[n][2], p[n][3]);
    }

    // ---- redistribute to PV A-fragments: aP[kk] = P[q=c16][k=kk*32+g*8..+7] ----
    union { uint32_t d[4]; short8 s; } aPu[2];
#pragma unroll
    for (int kk = 0; kk < 2; ++kk)
#pragma unroll
      for (int wd = 0; wd < 4; ++wd) {
        const int src = (2 * (g & 1) + (wd >> 1)) * 16 + c16;
        const uint32_t v0 = (uint32_t)__shfl((int)pk[kk * 2][wd & 1], src, 64);
        const uint32_t v1 = (uint32_t)__shfl((int)pk[kk * 2 + 1][wd & 1], src, 64);
        aPu[kk].d[wd] = (g >= 2) ? v1 : v0;
      }

    // ---- PV (unchanged layout: D row = q = g*4+j, col = d = c16) ----
#pragma unroll
    for (int dt = 0; dt < 8; ++dt) {
      const int r = dt * 16 + c16; // d row in Vl
#pragma unroll
      for (int kk = 0; kk < 2; ++kk) {
        const int cch = (kk * 4 + g) ^ (r & 7);
        short8 bV = *reinterpret_cast<const short8*>(&Vc[r * 64 + cch * 8]);
        accO[dt] = __builtin_amdgcn_mfma_f32_16x16x32_bf16(aPu[kk].s, bV, accO[dt], 0, 0, 0);
      }
    }
    __syncthreads(); // next buffer staged + all waves done reading cur
    cur ^= 1;
  }

  // ---- epilogue: fetch per-row 1/l via shfl, store bf16 [B,T,D] ----
  float linv[4];
#pragma unroll
  for (int j = 0; j < 4; ++j) linv[j] = 1.0f / __shfl(l_s, g * 4 + j, 64);
#pragma unroll
  for (int j = 0; j < 4; ++j) {
    const size_t rowoff = (size_t)(b * 1024 + q0w + g * 4 + j) * 1024 + h * 128;
#pragma unroll
    for (int dt = 0; dt < 8; ++dt)
      attnb[rowoff + dt * 16 + c16] = f2bf(accO[dt][j] * linv[j]);
  }
}

extern "C" void kernel_launch(void* const* d_in, const int* in_sizes, int n_in,
                              void* d_out, int out_size, void* d_ws, size_t ws_size,
                              hipStream_t stream) {
  const float* x = (const float*)d_in[0];
  const float* Wqkv = (const float*)d_in[1];
  const float* Wout = (const float*)d_in[2];
  const float* hscale = (const float*)d_in[3];
  const float* hdirs = (const float*)d_in[4];
  float* out = (float*)d_out;

  char* ws = (char*)d_ws;
  short* xb = (short*)(ws);                                  // 8 MB (dead after gemm1)
  short* wqkvT = (short*)(ws + (size_t)8 * 1024 * 1024);     // 6 MB
  short* woutT = (short*)(ws + (size_t)14 * 1024 * 1024);    // 2 MB
  short* qkvb = (short*)(ws + (size_t)16 * 1024 * 1024);     // 24 MB
  short* vT = (short*)(ws + (size_t)40 * 1024 * 1024);       // 8 MB
  short* attnb = (short*)(ws + (size_t)48 * 1024 * 1024);    // 8 MB
  float* kproj = (float*)(ws);                               // 128 KB, reuses dead xb region

  cvt_kernel<<<2048, 256, 0, stream>>>(x, xb, (4 * 1024 * 1024) / 4);
  tcvt_kernel<<<dim3(96, 32), 256, 0, stream>>>(Wqkv, wqkvT, 1024, 3072);
  tcvt_kernel<<<dim3(32, 32), 256, 0, stream>>>(Wout, woutT, 1024, 1024);
  // gemm1: M=4096 x N=3072 x K=1024, 256^2 8-phase, grid 16*12=192 (192%8==0)
  gemm256_kernel<1><<<192, 512, 0, stream>>>(xb, wqkvT, (void*)qkvb, 1024, 3072, 12);
  kproj_kernel<<<128, 256, 0, stream>>>(qkvb, hdirs, kproj);
  vtrans_kernel<<<dim3(16, 16, 4), 256, 0, stream>>>(qkvb, vT);
  attn_kernel<<<512, 256, 0, stream>>>(qkvb, vT, hscale, hdirs, kproj, attnb);
  gemm_kernel<0><<<dim3(8, 32), 256, 0, stream>>>(attnb, woutT, out, 1024, 1024);
}

// Round 8
// 118.700 us; speedup vs baseline: 1.0587x; 1.0343x over previous
//
#include <hip/hip_runtime.h>
#include <stdint.h>

typedef __attribute__((ext_vector_type(8))) short short8;
typedef __attribute__((ext_vector_type(4))) short short4v;
typedef __attribute__((ext_vector_type(4))) float f32x4;

__device__ __forceinline__ short f2bf(float x) {
  union { float f; uint32_t u; } c; c.f = x;
  uint32_t r = (c.u + 0x7FFFu + ((c.u >> 16) & 1u)) >> 16;
  return (short)r;
}
__device__ __forceinline__ float b2f(short s) {
  union { uint32_t u; float f; } c; c.u = ((uint32_t)(uint16_t)s) << 16;
  return c.f;
}
__device__ __forceinline__ uint32_t pack2bf(float lo, float hi) {
  return ((uint32_t)(uint16_t)f2bf(hi) << 16) | (uint32_t)(uint16_t)f2bf(lo);
}

// ---------------- fp32 -> bf16 convert (vectorized) ----------------
__global__ __launch_bounds__(256) void cvt_kernel(const float* __restrict__ in,
                                                  short* __restrict__ out, int n4) {
  int i = blockIdx.x * 256 + threadIdx.x;
  const int stride = gridDim.x * 256;
  for (; i < n4; i += stride) {
    float4 v = reinterpret_cast<const float4*>(in)[i];
    short4v o;
    o.x = f2bf(v.x); o.y = f2bf(v.y); o.z = f2bf(v.z); o.w = f2bf(v.w);
    reinterpret_cast<short4v*>(out)[i] = o;
  }
}

// ------------- fp32 [K][N] -> bf16 [N][K] transpose-convert -------------
__global__ __launch_bounds__(256) void tcvt_kernel(const float* __restrict__ in,
                                                   short* __restrict__ out, int K, int N) {
  __shared__ __align__(16) short tile[32][33];
  const int nb = blockIdx.x * 32, kb = blockIdx.y * 32;
  const int tx = threadIdx.x & 31, ty = threadIdx.x >> 5; // 32 x 8
#pragma unroll
  for (int i = 0; i < 32; i += 8)
    tile[ty + i][tx] = f2bf(in[(size_t)(kb + ty + i) * N + nb + tx]);
  __syncthreads();
#pragma unroll
  for (int i = 0; i < 32; i += 8)
    out[(size_t)(nb + ty + i) * K + kb + tx] = tile[tx][ty + i];
}

// ------------- bf16 V-region transpose: qkv[b][kv][2048+c] -> vT[b][c][kv] -------------
__global__ __launch_bounds__(256) void vtrans_kernel(const short* __restrict__ qkvb,
                                                     short* __restrict__ vT) {
  __shared__ __align__(16) short tile[64][65];
  const int b = blockIdx.z;
  const int kv0 = blockIdx.x * 64, c0 = blockIdx.y * 64;
  const int tx = threadIdx.x & 15, ty = threadIdx.x >> 4; // 16 x 16
  const short* src = qkvb + (size_t)(b * 1024) * 3072 + 2048;
#pragma unroll
  for (int i = 0; i < 64; i += 16) {
    int r = ty + i;
#pragma unroll
    for (int j = 0; j < 4; ++j)
      tile[r][tx * 4 + j] = src[(size_t)(kv0 + r) * 3072 + c0 + tx * 4 + j];
  }
  __syncthreads();
  short* dst = vT + (size_t)b * 1024 * 1024;
#pragma unroll
  for (int i = 0; i < 64; i += 16) {
    int cc = ty + i;
#pragma unroll
    for (int j = 0; j < 4; ++j)
      dst[(size_t)(c0 + cc) * 1024 + kv0 + tx * 4 + j] = tile[tx * 4 + j][cc];
  }
}

// ------------- k-projection precompute: kproj[bh][t] = dot(K[b,t,h,0:3], dir_h) -------------
__global__ __launch_bounds__(256) void kproj_kernel(const short* __restrict__ qkvb,
                                                    const float* __restrict__ hdirs,
                                                    float* __restrict__ kproj) {
  const int i = blockIdx.x * 256 + threadIdx.x; // over 32*1024
  const int bh = i >> 10, tt = i & 1023;
  const int b = bh >> 3, h = bh & 7;
  const float d0 = hdirs[h * 3], d1 = hdirs[h * 3 + 1], d2 = hdirs[h * 3 + 2];
  const short* kr = qkvb + (size_t)(b * 1024 + tt) * 3072 + 1024 + h * 128;
  kproj[i] = b2f(kr[0]) * d0 + b2f(kr[1]) * d1 + b2f(kr[2]) * d2;
}

// ---------------- bf16 MFMA GEMM: C[M][N] = A[M][K] * Bt[N][K]^T (128^2) ----------------
template <int OUT_BF16>
__global__ __launch_bounds__(256) void gemm_kernel(const short* __restrict__ A,
                                                   const short* __restrict__ Bt,
                                                   void* __restrict__ Cout,
                                                   int K, int ldc) {
  __shared__ __align__(16) short Al[2][128 * 32];
  __shared__ __align__(16) short Bl[2][128 * 32];
  const int t = threadIdx.x;
  const int lane = t & 63, w = t >> 6;
  const int wr = w >> 1, wc = w & 1;
  const int g = lane >> 4, c16 = lane & 15;
  const int row0 = blockIdx.y * 128, col0 = blockIdx.x * 128;

  f32x4 acc[4][4];
#pragma unroll
  for (int m = 0; m < 4; ++m)
#pragma unroll
    for (int n = 0; n < 4; ++n) {
      f32x4 z = {0.0f, 0.0f, 0.0f, 0.0f};
      acc[m][n] = z;
    }

  auto stage = [&](int buf, int kt) {
    const int k0 = kt * 32;
#pragma unroll
    for (int i = 0; i < 2; ++i) {
      const int qb = i * 256 + (t & 192); // wave-uniform chunk base
      const int q = qb + lane;
      const int r = q >> 2;
      const int c = (q & 3) ^ ((r >> 1) & 3);
      const short* ga = A + (size_t)(row0 + r) * K + k0 + c * 8;
      const short* gb = Bt + (size_t)(col0 + r) * K + k0 + c * 8;
      __builtin_amdgcn_global_load_lds((const __attribute__((address_space(1))) void*)ga,
                                       (__attribute__((address_space(3))) void*)&Al[buf][qb * 8],
                                       16, 0, 0);
      __builtin_amdgcn_global_load_lds((const __attribute__((address_space(1))) void*)gb,
                                       (__attribute__((address_space(3))) void*)&Bl[buf][qb * 8],
                                       16, 0, 0);
    }
  };

  stage(0, 0);
  __syncthreads();
  const int NK = K >> 5;
  int cur = 0;
  const int rA0 = wr * 64 + c16;
  const int rB0 = wc * 64 + c16;
  for (int kt = 0; kt < NK; ++kt) {
    if (kt + 1 < NK) stage(cur ^ 1, kt + 1);
    short8 aF[4], bF[4];
#pragma unroll
    for (int m = 0; m < 4; ++m) {
      const int r = rA0 + m * 16;
      const int c = g ^ ((r >> 1) & 3);
      aF[m] = *reinterpret_cast<const short8*>(&Al[cur][r * 32 + c * 8]);
    }
#pragma unroll
    for (int n = 0; n < 4; ++n) {
      const int r = rB0 + n * 16;
      const int c = g ^ ((r >> 1) & 3);
      bF[n] = *reinterpret_cast<const short8*>(&Bl[cur][r * 32 + c * 8]);
    }
#pragma unroll
    for (int m = 0; m < 4; ++m)
#pragma unroll
      for (int n = 0; n < 4; ++n)
        acc[m][n] = __builtin_amdgcn_mfma_f32_16x16x32_bf16(aF[m], bF[n], acc[m][n], 0, 0, 0);
    __syncthreads();
    cur ^= 1;
  }

  const int er = row0 + wr * 64 + g * 4;
  const int ec = col0 + wc * 64 + c16;
#pragma unroll
  for (int m = 0; m < 4; ++m)
#pragma unroll
    for (int n = 0; n < 4; ++n)
#pragma unroll
      for (int j = 0; j < 4; ++j) {
        const size_t off = (size_t)(er + m * 16 + j) * ldc + ec + n * 16;
        if (OUT_BF16)
          ((short*)Cout)[off] = f2bf(acc[m][n][j]);
        else
          ((float*)Cout)[off] = acc[m][n][j];
      }
}

// ---------------- fused causal attention with trigram geo bias ----------------
// Swapped-QK^T structure: compute mfma(K, Q) so each lane holds a full P row
// (q = c16) in registers. Softmax = in-register + 2 shfl_xor. P_lds deleted;
// PV A-fragments rebuilt via 16 shfl + 8 selects. exp2-domain softmax.
// 512 blocks at 2/CU, all co-resident. Balanced pairing: under round-robin
// dispatch, CU k hosts blocks k and k+256; qt = bid<256 ? 15-(bid>>5)
// : (bid>>5)-8 makes each CU's tile total exactly (qt+1)+(16-qt) = 17.
__global__ __launch_bounds__(256) void attn_kernel(const short* __restrict__ qkvb,
                                                   const short* __restrict__ vT,
                                                   const float* __restrict__ head_scales,
                                                   const float* __restrict__ hdirs,
                                                   const float* __restrict__ kproj,
                                                   short* __restrict__ attnb) {
  __shared__ __align__(16) short Kl[2][64 * 128];
  __shared__ __align__(16) short Vl[2][128 * 64];
  __shared__ float kp_lds[2][64];

  const int bid = blockIdx.x;                       // 0..511
  const int bh = (bid & 7) * 4 + ((bid >> 3) & 3);  // 4 bh per XCD
  const int r2 = bid >> 5;                          // 0..15
  const int qt = (bid < 256) ? (15 - r2) : (r2 - 8); // balanced CU pairing
  const int b = bh >> 3, h = bh & 7;
  const int t = threadIdx.x, lane = t & 63, w = t >> 6;
  const int g = lane >> 4, c16 = lane & 15;
  const int q0w = qt * 64 + w * 16;
  const int q_abs = q0w + c16; // this lane's q row

  const short* qbase = qkvb + (size_t)(b * 1024) * 3072 + h * 128;
  const short* kbase = qbase + 1024;
  const short* vtb = vT + (size_t)bh * 128 * 1024;
  const float* kp = kproj + bh * 1024;

  const float LOG2E = 1.44269504088896f;
  const float scale2 = 0.08838834764831845f * 1.44269504088896f; // /sqrt(128)*log2e

  // Q fragments (B-operand): col = c16 (q row), k = kk*32 + g*8 .. +7
  short8 aQ[4];
  float hqp; // hs * qproj(row c16) * log2e
  {
    const short* qr = qbase + (size_t)(q0w + c16) * 3072;
#pragma unroll
    for (int kk = 0; kk < 4; ++kk)
      aQ[kk] = *reinterpret_cast<const short8*>(qr + kk * 32 + g * 8);
    const float hs = head_scales[h];
    hqp = hs * LOG2E *
          (b2f(qr[0]) * hdirs[h * 3] + b2f(qr[1]) * hdirs[h * 3 + 1] + b2f(qr[2]) * hdirs[h * 3 + 2]);
  }

  float m_s = -1e30f, l_s = 0.0f; // per q-row (= c16), replicated across g
  f32x4 accO[8];
#pragma unroll
  for (int d = 0; d < 8; ++d) {
    f32x4 z = {0.0f, 0.0f, 0.0f, 0.0f};
    accO[d] = z;
  }

  auto stageKV = [&](int buf, int kvt) {
    const int kv0 = kvt * 64;
#pragma unroll
    for (int i = 0; i < 4; ++i) {
      const int s = w * 4 + i;
      {
        const int r = s * 4 + g;            // kv row
        const int c = c16 ^ (r & 7);        // global 16B chunk (16/row)
        const short* ga = kbase + (size_t)(kv0 + r) * 3072 + c * 8;
        __builtin_amdgcn_global_load_lds((const __attribute__((address_space(1))) void*)ga,
                                         (__attribute__((address_space(3))) void*)&Kl[buf][s * 512],
                                         16, 0, 0);
      }
      {
        const int r = s * 8 + (lane >> 3);  // d row
        const int c = (lane & 7) ^ (r & 7); // global 16B chunk (8/row)
        const short* ga = vtb + (size_t)r * 1024 + kv0 + c * 8;
        __builtin_amdgcn_global_load_lds((const __attribute__((address_space(1))) void*)ga,
                                         (__attribute__((address_space(3))) void*)&Vl[buf][s * 512],
                                         16, 0, 0);
      }
    }
    if (lane < 16) kp_lds[buf][w * 16 + lane] = kp[kv0 + w * 16 + lane];
  };

  const int nkv = qt + 1;
  stageKV(0, 0);
  __syncthreads();
  int cur = 0;
  for (int kvt = 0; kvt < nkv; ++kvt) {
    const int kv0 = kvt * 64;
    if (kvt + 1 < nkv) stageKV(cur ^ 1, kvt + 1); // prefetch overlaps compute
    const short* Kc = Kl[cur];
    const short* Vc = Vl[cur];
    const float* kpc = kp_lds[cur];

    // ---- swapped QK^T: p[n][j] = P[k = n*16+g*4+j][q = c16] ----
    float p[4][4];
#pragma unroll
    for (int n = 0; n < 4; ++n) {
      f32x4 s4 = {0.0f, 0.0f, 0.0f, 0.0f};
      const int r = n * 16 + c16; // kv row within tile (A-operand row)
#pragma unroll
      for (int kk = 0; kk < 4; ++kk) {
        const int cch = (kk * 4 + g) ^ (r & 7);
        short8 bK = *reinterpret_cast<const short8*>(&Kc[r * 128 + cch * 8]);
        s4 = __builtin_amdgcn_mfma_f32_16x16x32_bf16(bK, aQ[kk], s4, 0, 0, 0);
      }
#pragma unroll
      for (int j = 0; j < 4; ++j) {
        const int kloc = n * 16 + g * 4 + j;
        const float v = s4[j] * scale2 + hqp * kpc[kloc];
        p[n][j] = (kv0 + kloc <= q_abs) ? v : -1e30f;
      }
    }

    // ---- row max: in-register tree + 2 shfl_xor ----
    float mx;
    {
      float a0 = fmaxf(fmaxf(p[0][0], p[0][1]), fmaxf(p[0][2], p[0][3]));
      float a1 = fmaxf(fmaxf(p[1][0], p[1][1]), fmaxf(p[1][2], p[1][3]));
      float a2 = fmaxf(fmaxf(p[2][0], p[2][1]), fmaxf(p[2][2], p[2][3]));
      float a3 = fmaxf(fmaxf(p[3][0], p[3][1]), fmaxf(p[3][2], p[3][3]));
      mx = fmaxf(fmaxf(a0, a1), fmaxf(a2, a3));
      mx = fmaxf(mx, __shfl_xor(mx, 16, 64));
      mx = fmaxf(mx, __shfl_xor(mx, 32, 64));
    }

    // ---- defer-max (THR = 8 nats = 11.54 in log2 domain) ----
    if (__any(mx - m_s > 11.54f)) {
      const float mn = fmaxf(m_s, mx);
      const float alpha = exp2f(m_s - mn);
      m_s = mn;
      l_s *= alpha;
      float aO[4];
#pragma unroll
      for (int j = 0; j < 4; ++j) aO[j] = __shfl(alpha, g * 4 + j, 64);
#pragma unroll
      for (int d = 0; d < 8; ++d)
#pragma unroll
        for (int j = 0; j < 4; ++j) accO[d][j] *= aO[j];
    }

    // ---- exp2 + row sum (tree + 2 shfl_xor) ----
    float s01 = 0.0f, s23 = 0.0f;
#pragma unroll
    for (int n = 0; n < 4; ++n) {
      float e0 = exp2f(p[n][0] - m_s), e1 = exp2f(p[n][1] - m_s);
      float e2 = exp2f(p[n][2] - m_s), e3 = exp2f(p[n][3] - m_s);
      p[n][0] = e0; p[n][1] = e1; p[n][2] = e2; p[n][3] = e3;
      if (n < 2) s01 += (e0 + e1) + (e2 + e3); else s23 += (e0 + e1) + (e2 + e3);
    }
    float sum = s01 + s23;
    sum += __shfl_xor(sum, 16, 64);
    sum += __shfl_xor(sum, 32, 64);
    l_s += sum;

    // ---- pack to bf16 pairs: pk[n][u] = {k = n*16+g*4+2u, +1} ----
    uint32_t pk[4][2];
#pragma unroll
    for (int n = 0; n < 4; ++n) {
      pk[n][0] = pack2bf(p[n][0], p[n][1]);
      pk[n][1] = pack2bf(p[n][2], p[n][3]);
    }

    // ---- redistribute to PV A-fragments: aP[kk] = P[q=c16][k=kk*32+g*8..+7] ----
    union { uint32_t d[4]; short8 s; } aPu[2];
#pragma unroll
    for (int kk = 0; kk < 2; ++kk)
#pragma unroll
      for (int wd = 0; wd < 4; ++wd) {
        const int src = (2 * (g & 1) + (wd >> 1)) * 16 + c16;
        const uint32_t v0 = (uint32_t)__shfl((int)pk[kk * 2][wd & 1], src, 64);
        const uint32_t v1 = (uint32_t)__shfl((int)pk[kk * 2 + 1][wd & 1], src, 64);
        aPu[kk].d[wd] = (g >= 2) ? v1 : v0;
      }

    // ---- PV (unchanged layout: D row = q = g*4+j, col = d = c16) ----
#pragma unroll
    for (int dt = 0; dt < 8; ++dt) {
      const int r = dt * 16 + c16; // d row in Vl
#pragma unroll
      for (int kk = 0; kk < 2; ++kk) {
        const int cch = (kk * 4 + g) ^ (r & 7);
        short8 bV = *reinterpret_cast<const short8*>(&Vc[r * 64 + cch * 8]);
        accO[dt] = __builtin_amdgcn_mfma_f32_16x16x32_bf16(aPu[kk].s, bV, accO[dt], 0, 0, 0);
      }
    }
    __syncthreads(); // next buffer staged + all waves done reading cur
    cur ^= 1;
  }

  // ---- epilogue: fetch per-row 1/l via shfl, store bf16 [B,T,D] ----
  float linv[4];
#pragma unroll
  for (int j = 0; j < 4; ++j) linv[j] = 1.0f / __shfl(l_s, g * 4 + j, 64);
#pragma unroll
  for (int j = 0; j < 4; ++j) {
    const size_t rowoff = (size_t)(b * 1024 + q0w + g * 4 + j) * 1024 + h * 128;
#pragma unroll
    for (int dt = 0; dt < 8; ++dt)
      attnb[rowoff + dt * 16 + c16] = f2bf(accO[dt][j] * linv[j]);
  }
}

extern "C" void kernel_launch(void* const* d_in, const int* in_sizes, int n_in,
                              void* d_out, int out_size, void* d_ws, size_t ws_size,
                              hipStream_t stream) {
  const float* x = (const float*)d_in[0];
  const float* Wqkv = (const float*)d_in[1];
  const float* Wout = (const float*)d_in[2];
  const float* hscale = (const float*)d_in[3];
  const float* hdirs = (const float*)d_in[4];
  float* out = (float*)d_out;

  char* ws = (char*)d_ws;
  short* xb = (short*)(ws);                                  // 8 MB (dead after gemm1)
  short* wqkvT = (short*)(ws + (size_t)8 * 1024 * 1024);     // 6 MB
  short* woutT = (short*)(ws + (size_t)14 * 1024 * 1024);    // 2 MB
  short* qkvb = (short*)(ws + (size_t)16 * 1024 * 1024);     // 24 MB
  short* vT = (short*)(ws + (size_t)40 * 1024 * 1024);       // 8 MB
  short* attnb = (short*)(ws + (size_t)48 * 1024 * 1024);    // 8 MB
  float* kproj = (float*)(ws);                               // 128 KB, reuses dead xb region

  cvt_kernel<<<2048, 256, 0, stream>>>(x, xb, (4 * 1024 * 1024) / 4);
  tcvt_kernel<<<dim3(96, 32), 256, 0, stream>>>(Wqkv, wqkvT, 1024, 3072);
  tcvt_kernel<<<dim3(32, 32), 256, 0, stream>>>(Wout, woutT, 1024, 1024);
  gemm_kernel<1><<<dim3(24, 32), 256, 0, stream>>>(xb, wqkvT, (void*)qkvb, 1024, 3072);
  kproj_kernel<<<128, 256, 0, stream>>>(qkvb, hdirs, kproj);
  vtrans_kernel<<<dim3(16, 16, 4), 256, 0, stream>>>(qkvb, vT);
  attn_kernel<<<512, 256, 0, stream>>>(qkvb, vT, hscale, hdirs, kproj, attnb);
  gemm_kernel<0><<<dim3(8, 32), 256, 0, stream>>>(attnb, woutT, out, 1024, 1024);
}